// Round 2
// baseline (291.156 us; speedup 1.0000x reference)
//
#include <hip/hip_runtime.h>
#include <math.h>

#define DD 2048
#define HH 1152
#define NAA 18
#define KK 64
#define RR 10

__device__ __forceinline__ float wred(float v) {
#pragma unroll
  for (int off = 32; off > 0; off >>= 1) v += __shfl_down(v, off);
  return v;
}

__device__ __forceinline__ float sigf(float x) { return 1.f / (1.f + expf(-x)); }

// Kernel 1: s = relu(Wms @ z + bms), z = relu(Wp@x+bp) recomputed into LDS.
// Also zeroes the 32 scalar accumulators (ws is poisoned 0xAA each call).
__global__ void k_s(const float* __restrict__ x, const float* __restrict__ Wp,
                    const float* __restrict__ bp, const float* __restrict__ Wms,
                    const float* __restrict__ bms, float* __restrict__ s_out,
                    float* __restrict__ scal) {
  __shared__ float z[DD];
  const float x0 = x[0], x1 = x[1];
  for (int i = threadIdx.x; i < DD; i += blockDim.x) {
    float v = fmaf(Wp[2 * i], x0, fmaf(Wp[2 * i + 1], x1, bp[i]));
    z[i] = fmaxf(v, 0.f);
  }
  if (blockIdx.x == 0 && threadIdx.x < 32) scal[threadIdx.x] = 0.f;
  __syncthreads();
  const int lane = threadIdx.x & 63;
  const int gw = blockIdx.x * (blockDim.x >> 6) + (threadIdx.x >> 6);
  const int nw = gridDim.x * (blockDim.x >> 6);
  for (int row = gw; row < DD; row += nw) {
    const float4* wr = (const float4*)(Wms + (size_t)row * DD);
    float acc = 0.f;
#pragma unroll
    for (int it = 0; it < 8; ++it) {
      float4 w4 = wr[it * 64 + lane];
      float4 z4 = *(const float4*)&z[4 * (it * 64 + lane)];
      acc = fmaf(w4.x, z4.x, acc); acc = fmaf(w4.y, z4.y, acc);
      acc = fmaf(w4.z, z4.z, acc); acc = fmaf(w4.w, z4.w, acc);
    }
    acc = wred(acc);
    if (lane == 0) s_out[row] = fmaxf(acc + bms[row], 0.f);
  }
}

// Kernel 2: fused manager + worker LSTM gate matvecs (12800 rows, 193 MB).
__global__ void k_gates(const float* __restrict__ x, const float* __restrict__ Wp,
                        const float* __restrict__ bp, const float* __restrict__ s_in,
                        const int* __restrict__ tick,
                        const float* __restrict__ Wih_m, const float* __restrict__ Whh_m,
                        const float* __restrict__ bih_m, const float* __restrict__ bhh_m,
                        const float* __restrict__ hn_m,
                        const float* __restrict__ Wih_w, const float* __restrict__ Whh_w,
                        const float* __restrict__ bih_w, const float* __restrict__ bhh_w,
                        const float* __restrict__ hn_w,
                        float* __restrict__ gates_m, float* __restrict__ gates_w) {
  __shared__ float sv[DD];
  __shared__ float zv[DD];
  __shared__ float hm[DD];
  __shared__ float hw[HH];
  const int tk = *tick;
  const float x0 = x[0], x1 = x[1];
  for (int i = threadIdx.x; i < DD; i += blockDim.x) {
    sv[i] = s_in[i];
    float v = fmaf(Wp[2 * i], x0, fmaf(Wp[2 * i + 1], x1, bp[i]));
    zv[i] = fmaxf(v, 0.f);
    hm[i] = hn_m[tk * DD + i];
  }
  for (int i = threadIdx.x; i < HH; i += blockDim.x) hw[i] = hn_w[i];
  __syncthreads();
  const int lane = threadIdx.x & 63;
  const int gw = blockIdx.x * (blockDim.x >> 6) + (threadIdx.x >> 6);
  const int nw = gridDim.x * (blockDim.x >> 6);
  const int nrows = 4 * DD + 4 * HH;  // 8192 + 4608
  for (int row = gw; row < nrows; row += nw) {
    if (row < 4 * DD) {
      const float4* a = (const float4*)(Wih_m + (size_t)row * DD);
      const float4* b = (const float4*)(Whh_m + (size_t)row * DD);
      float acc = 0.f;
#pragma unroll
      for (int it = 0; it < 8; ++it) {
        float4 a4 = a[it * 64 + lane];
        float4 s4 = *(const float4*)&sv[4 * (it * 64 + lane)];
        acc = fmaf(a4.x, s4.x, acc); acc = fmaf(a4.y, s4.y, acc);
        acc = fmaf(a4.z, s4.z, acc); acc = fmaf(a4.w, s4.w, acc);
        float4 b4 = b[it * 64 + lane];
        float4 h4 = *(const float4*)&hm[4 * (it * 64 + lane)];
        acc = fmaf(b4.x, h4.x, acc); acc = fmaf(b4.y, h4.y, acc);
        acc = fmaf(b4.z, h4.z, acc); acc = fmaf(b4.w, h4.w, acc);
      }
      acc = wred(acc);
      if (lane == 0) gates_m[row] = acc + bih_m[row] + bhh_m[row];
    } else {
      const int j = row - 4 * DD;
      const float4* a = (const float4*)(Wih_w + (size_t)j * DD);
      float acc = 0.f;
#pragma unroll
      for (int it = 0; it < 8; ++it) {
        float4 a4 = a[it * 64 + lane];
        float4 z4 = *(const float4*)&zv[4 * (it * 64 + lane)];
        acc = fmaf(a4.x, z4.x, acc); acc = fmaf(a4.y, z4.y, acc);
        acc = fmaf(a4.z, z4.z, acc); acc = fmaf(a4.w, z4.w, acc);
      }
      const float4* b = (const float4*)(Whh_w + (size_t)j * HH);
#pragma unroll
      for (int it = 0; it < 4; ++it) {
        float4 b4 = b[it * 64 + lane];
        float4 h4 = *(const float4*)&hw[4 * (it * 64 + lane)];
        acc = fmaf(b4.x, h4.x, acc); acc = fmaf(b4.y, h4.y, acc);
        acc = fmaf(b4.z, h4.z, acc); acc = fmaf(b4.w, h4.w, acc);
      }
      if (lane < 32) {
        float4 b4 = b[256 + lane];
        float4 h4 = *(const float4*)&hw[4 * (256 + lane)];
        acc = fmaf(b4.x, h4.x, acc); acc = fmaf(b4.y, h4.y, acc);
        acc = fmaf(b4.z, h4.z, acc); acc = fmaf(b4.w, h4.w, acc);
      }
      acc = wred(acc);
      if (lane == 0) gates_w[j] = acc + bih_w[j] + bhh_w[j];
    }
  }
}

// Kernel 3: LSTM elementwise (manager + worker), g_hat, and all scalar
// reductions (norm2, m_value, w_value, cos numerators/denominators).
// scal layout: 0=norm2 1=mval 2=wval 3=num9h 4..13=dd2[0..9] 14..22=num[0..8] 23..31=gg2[0..8]
__global__ void k_cell(const float* __restrict__ gates_m, const float* __restrict__ gates_w,
                       const int* __restrict__ tick, const float* __restrict__ hn_m,
                       const float* __restrict__ cn_m, const float* __restrict__ cn_w,
                       const float* __restrict__ Wmv, const float* __restrict__ Wc,
                       const float* __restrict__ goals, const float* __restrict__ states,
                       const float* __restrict__ s_in,
                       float* __restrict__ g_hat, float* __restrict__ goalsA,
                       float* __restrict__ u_flat, float* __restrict__ scal) {
  const int t = blockIdx.x * blockDim.x + threadIdx.x;
  const int tk = *tick;
  float r_norm2 = 0.f, r_mval = 0.f, r_wval = 0.f, r_num9h = 0.f;
  float r_dd2[10], r_num[9], r_gg2[9];
#pragma unroll
  for (int r = 0; r < 10; ++r) r_dd2[r] = 0.f;
#pragma unroll
  for (int r = 0; r < 9; ++r) { r_num[r] = 0.f; r_gg2[r] = 0.f; }

  if (t < DD) {
    const int d = t;
    float gi = gates_m[d], gf = gates_m[DD + d], gg = gates_m[2 * DD + d], go = gates_m[3 * DD + d];
    float c = cn_m[tk * DD + d];
    float c2 = sigf(gf) * c + sigf(gi) * tanhf(gg);
    float hnew = sigf(go) * tanhf(c2);
    float sum = hnew;
#pragma unroll
    for (int r = 0; r < RR; ++r) sum += (r == tk) ? 0.f : hn_m[r * DD + d];
    float gh = sum * (1.f / RR);
    g_hat[d] = gh;
    r_norm2 = gh * gh;
    r_mval = Wmv[d] * gh;
    float ga = 0.f;
    float sd = s_in[d];
#pragma unroll
    for (int r = 0; r < RR; ++r) {
      float diff = sd - states[(r + 1) * DD + d];
      r_dd2[r] = diff * diff;
      if (r < 9) {
        float gl = goals[(r + 1) * DD + d];
        ga += gl;
        r_num[r] = diff * gl;
        r_gg2[r] = gl * gl;
      } else {
        r_num9h = diff * gh;  // dot(diff9, g_hat); scaled by rnorm at finalize
      }
    }
    goalsA[d] = ga;
  } else if (t < DD + HH) {
    const int j = t - DD;
    float gi = gates_w[j], gf = gates_w[HH + j], gg = gates_w[2 * HH + j], go = gates_w[3 * HH + j];
    float c = cn_w[j];
    float c2 = sigf(gf) * c + sigf(gi) * tanhf(gg);
    float u = sigf(go) * tanhf(c2);
    u_flat[j] = u;
    r_wval = Wc[j] * u;
  }

  r_norm2 = wred(r_norm2); r_mval = wred(r_mval);
  r_wval = wred(r_wval);   r_num9h = wred(r_num9h);
#pragma unroll
  for (int r = 0; r < 10; ++r) r_dd2[r] = wred(r_dd2[r]);
#pragma unroll
  for (int r = 0; r < 9; ++r) { r_num[r] = wred(r_num[r]); r_gg2[r] = wred(r_gg2[r]); }
  if ((threadIdx.x & 63) == 0) {
    atomicAdd(&scal[0], r_norm2);
    atomicAdd(&scal[1], r_mval);
    atomicAdd(&scal[2], r_wval);
    atomicAdd(&scal[3], r_num9h);
#pragma unroll
    for (int r = 0; r < 10; ++r) atomicAdd(&scal[4 + r], r_dd2[r]);
#pragma unroll
    for (int r = 0; r < 9; ++r) {
      atomicAdd(&scal[14 + r], r_num[r]);
      atomicAdd(&scal[23 + r], r_gg2[r]);
    }
  }
}

// Kernel 4: w = Wphi @ (sum(goals[1:]) + g_hat * rnorm), one wave per row.
__global__ void k_w(const float* __restrict__ Wphi, const float* __restrict__ g_hat,
                    const float* __restrict__ goalsA, const float* __restrict__ scal,
                    float* __restrict__ wv) {
  __shared__ float vsum[DD];
  const float rn = 1.f / fmaxf(sqrtf(scal[0]), 1e-12f);
  for (int i = threadIdx.x; i < DD; i += blockDim.x)
    vsum[i] = fmaf(g_hat[i], rn, goalsA[i]);
  __syncthreads();
  const int lane = threadIdx.x & 63;
  const int gw = blockIdx.x * (blockDim.x >> 6) + (threadIdx.x >> 6);
  if (gw < KK) {
    const float4* a = (const float4*)(Wphi + (size_t)gw * DD);
    float acc = 0.f;
#pragma unroll
    for (int it = 0; it < 8; ++it) {
      float4 a4 = a[it * 64 + lane];
      float4 v4 = *(const float4*)&vsum[4 * (it * 64 + lane)];
      acc = fmaf(a4.x, v4.x, acc); acc = fmaf(a4.y, v4.y, acc);
      acc = fmaf(a4.z, v4.z, acc); acc = fmaf(a4.w, v4.w, acc);
    }
    acc = wred(acc);
    if (lane == 0) wv[gw] = acc;
  }
}

// Kernel 5: logits + scalar outputs.
__global__ void k_final(const float* __restrict__ u_flat, const float* __restrict__ wv,
                        const float* __restrict__ scal, const float* __restrict__ bmv,
                        const float* __restrict__ bc, float* __restrict__ out) {
  __shared__ float wl[KK];
  if (threadIdx.x < KK) wl[threadIdx.x] = wv[threadIdx.x];
  __syncthreads();
  const int lane = threadIdx.x & 63;
  const int wid = threadIdx.x >> 6;
  const int nw = blockDim.x >> 6;
  for (int a = wid; a < NAA; a += nw) {
    float acc = u_flat[a * KK + lane] * wl[lane];
    acc = wred(acc);
    if (lane == 0) out[a] = acc;
  }
  if (threadIdx.x == 0) {
    float nrm = sqrtf(scal[0]);
    float rn = 1.f / fmaxf(nrm, 1e-12f);
    float gnorm = nrm * rn;  // ||g|| exactly as reference: ||g_hat||/max(||g_hat||,1e-12)
    float csum = 0.f;
    for (int r = 0; r < 9; ++r) {
      float den = fmaxf(sqrtf(scal[4 + r]), 1e-8f) * fmaxf(sqrtf(scal[23 + r]), 1e-8f);
      csum += scal[14 + r] / den;
    }
    float den9 = fmaxf(sqrtf(scal[13]), 1e-8f) * fmaxf(gnorm, 1e-8f);
    csum += (scal[3] * rn) / den9;
    out[NAA] = (float)DD * csum / 10.f;   // w_intrinsic_reward
    out[NAA + 1] = scal[2] + bc[0];       // w_value
    out[NAA + 2] = scal[1] + bmv[0];      // m_value
  }
}

extern "C" void kernel_launch(void* const* d_in, const int* in_sizes, int n_in,
                              void* d_out, int out_size, void* d_ws, size_t ws_size,
                              hipStream_t stream) {
  const float* x      = (const float*)d_in[0];
  const float* Wp     = (const float*)d_in[1];
  const float* bp     = (const float*)d_in[2];
  const float* Wms    = (const float*)d_in[3];
  const float* bms    = (const float*)d_in[4];
  const float* Wih_m  = (const float*)d_in[5];
  const float* Whh_m  = (const float*)d_in[6];
  const float* bih_m  = (const float*)d_in[7];
  const float* bhh_m  = (const float*)d_in[8];
  const float* hn_m   = (const float*)d_in[9];
  const float* cn_m   = (const float*)d_in[10];
  const float* Wmv    = (const float*)d_in[11];
  const float* bmv    = (const float*)d_in[12];
  const float* Wih_w  = (const float*)d_in[13];
  const float* Whh_w  = (const float*)d_in[14];
  const float* bih_w  = (const float*)d_in[15];
  const float* bhh_w  = (const float*)d_in[16];
  const float* hn_w   = (const float*)d_in[17];
  const float* cn_w   = (const float*)d_in[18];
  const float* Wphi   = (const float*)d_in[19];
  const float* Wc     = (const float*)d_in[20];
  const float* bc     = (const float*)d_in[21];
  const float* states = (const float*)d_in[22];
  const float* goals  = (const float*)d_in[23];
  const int*   tick   = (const int*)d_in[24];

  float* ws      = (float*)d_ws;
  float* gates_m = ws;             // 8192
  float* gates_w = ws + 8192;      // 4608
  float* s_buf   = ws + 12800;     // 2048
  float* g_hat   = ws + 14848;     // 2048
  float* goalsA  = ws + 16896;     // 2048
  float* u_flat  = ws + 18944;     // 1152
  float* wvec    = ws + 20096;     // 64
  float* scal    = ws + 20160;     // 32
  float* out     = (float*)d_out;

  hipLaunchKernelGGL(k_s, dim3(256), dim3(256), 0, stream,
                     x, Wp, bp, Wms, bms, s_buf, scal);
  hipLaunchKernelGGL(k_gates, dim3(640), dim3(256), 0, stream,
                     x, Wp, bp, s_buf, tick,
                     Wih_m, Whh_m, bih_m, bhh_m, hn_m,
                     Wih_w, Whh_w, bih_w, bhh_w, hn_w,
                     gates_m, gates_w);
  hipLaunchKernelGGL(k_cell, dim3(13), dim3(256), 0, stream,
                     gates_m, gates_w, tick, hn_m, cn_m, cn_w, Wmv, Wc,
                     goals, states, s_buf, g_hat, goalsA, u_flat, scal);
  hipLaunchKernelGGL(k_w, dim3(16), dim3(256), 0, stream,
                     Wphi, g_hat, goalsA, scal, wvec);
  hipLaunchKernelGGL(k_final, dim3(1), dim3(512), 0, stream,
                     u_flat, wvec, scal, bmv, bc, out);
}

// Round 4
// 288.467 us; speedup vs baseline: 1.0093x; 1.0093x over previous
//
#include <hip/hip_runtime.h>
#include <math.h>

#define DD 2048
#define HH 1152
#define NAA 18
#define KK 64
#define RR 10

__device__ __forceinline__ float wred(float v) {
#pragma unroll
  for (int off = 32; off > 0; off >>= 1) v += __shfl_down(v, off);
  return v;
}

__device__ __forceinline__ float sigf(float x) { return 1.f / (1.f + expf(-x)); }

// Kernel A: worker LSTM gate matvec (4608 rows, 59 MB). Independent of s.
// One row per wave, register-batched loads (8+5 float4 in flight).
__global__ __launch_bounds__(256, 4) void k_wg(
    const float* __restrict__ x, const float* __restrict__ Wp,
    const float* __restrict__ bp,
    const float* __restrict__ Wih_w, const float* __restrict__ Whh_w,
    const float* __restrict__ bih_w, const float* __restrict__ bhh_w,
    const float* __restrict__ hn_w, float* __restrict__ gates_w) {
  __shared__ float zv[DD];
  __shared__ float hw[HH];
  const float x0 = x[0], x1 = x[1];
  for (int i = threadIdx.x; i < DD; i += blockDim.x) {
    float v = fmaf(Wp[2 * i], x0, fmaf(Wp[2 * i + 1], x1, bp[i]));
    zv[i] = fmaxf(v, 0.f);
  }
  for (int i = threadIdx.x; i < HH; i += blockDim.x) hw[i] = hn_w[i];
  __syncthreads();
  const int lane = threadIdx.x & 63;
  const int row = blockIdx.x * (blockDim.x >> 6) + (threadIdx.x >> 6);
  if (row >= 4 * HH) return;
  const float4* a = (const float4*)(Wih_w + (size_t)row * DD);
  const float4* b = (const float4*)(Whh_w + (size_t)row * HH);
  float4 ra[8], rb[5];
#pragma unroll
  for (int it = 0; it < 8; ++it) ra[it] = a[it * 64 + lane];
#pragma unroll
  for (int it = 0; it < 4; ++it) rb[it] = b[it * 64 + lane];
  rb[4] = (lane < 32) ? b[256 + lane] : make_float4(0.f, 0.f, 0.f, 0.f);
  float acc = 0.f;
#pragma unroll
  for (int it = 0; it < 8; ++it) {
    float4 z4 = *(const float4*)&zv[4 * (it * 64 + lane)];
    acc = fmaf(ra[it].x, z4.x, acc); acc = fmaf(ra[it].y, z4.y, acc);
    acc = fmaf(ra[it].z, z4.z, acc); acc = fmaf(ra[it].w, z4.w, acc);
  }
#pragma unroll
  for (int it = 0; it < 4; ++it) {
    float4 h4 = *(const float4*)&hw[4 * (it * 64 + lane)];
    acc = fmaf(rb[it].x, h4.x, acc); acc = fmaf(rb[it].y, h4.y, acc);
    acc = fmaf(rb[it].z, h4.z, acc); acc = fmaf(rb[it].w, h4.w, acc);
  }
  {
    float4 h4 = *(const float4*)&hw[4 * (256 + (lane & 31))];
    acc = fmaf(rb[4].x, h4.x, acc); acc = fmaf(rb[4].y, h4.y, acc);
    acc = fmaf(rb[4].z, h4.z, acc); acc = fmaf(rb[4].w, h4.w, acc);
  }
  acc = wred(acc);
  if (lane == 0) gates_w[row] = acc + bih_w[row] + bhh_w[row];
}

// Kernel B: s = relu(Wms @ z + bms) (16.8 MB). Also zeroes scal accumulators.
__global__ __launch_bounds__(256, 4) void k_s(
    const float* __restrict__ x, const float* __restrict__ Wp,
    const float* __restrict__ bp, const float* __restrict__ Wms,
    const float* __restrict__ bms, float* __restrict__ s_out,
    float* __restrict__ scal) {
  __shared__ float z[DD];
  const float x0 = x[0], x1 = x[1];
  for (int i = threadIdx.x; i < DD; i += blockDim.x) {
    float v = fmaf(Wp[2 * i], x0, fmaf(Wp[2 * i + 1], x1, bp[i]));
    z[i] = fmaxf(v, 0.f);
  }
  if (blockIdx.x == 0 && threadIdx.x < 32) scal[threadIdx.x] = 0.f;
  __syncthreads();
  const int lane = threadIdx.x & 63;
  const int row = blockIdx.x * (blockDim.x >> 6) + (threadIdx.x >> 6);
  if (row >= DD) return;
  const float4* wr = (const float4*)(Wms + (size_t)row * DD);
  float4 rw[8];
#pragma unroll
  for (int it = 0; it < 8; ++it) rw[it] = wr[it * 64 + lane];
  float acc = 0.f;
#pragma unroll
  for (int it = 0; it < 8; ++it) {
    float4 z4 = *(const float4*)&z[4 * (it * 64 + lane)];
    acc = fmaf(rw[it].x, z4.x, acc); acc = fmaf(rw[it].y, z4.y, acc);
    acc = fmaf(rw[it].z, z4.z, acc); acc = fmaf(rw[it].w, z4.w, acc);
  }
  acc = wred(acc);
  if (lane == 0) s_out[row] = fmaxf(acc + bms[row], 0.f);
}

// Kernel C: manager LSTM gate matvec (8192 rows, 134 MB). One row per wave,
// 16 float4 loads in flight per wave.
__global__ __launch_bounds__(256, 4) void k_mg(
    const float* __restrict__ s_in, const int* __restrict__ tick,
    const float* __restrict__ Wih_m, const float* __restrict__ Whh_m,
    const float* __restrict__ bih_m, const float* __restrict__ bhh_m,
    const float* __restrict__ hn_m, float* __restrict__ gates_m) {
  __shared__ float sv[DD];
  __shared__ float hm[DD];
  const int tk = *tick;
  for (int i = threadIdx.x; i < DD; i += blockDim.x) {
    sv[i] = s_in[i];
    hm[i] = hn_m[tk * DD + i];
  }
  __syncthreads();
  const int lane = threadIdx.x & 63;
  const int row = blockIdx.x * (blockDim.x >> 6) + (threadIdx.x >> 6);
  if (row >= 4 * DD) return;
  const float4* a = (const float4*)(Wih_m + (size_t)row * DD);
  const float4* b = (const float4*)(Whh_m + (size_t)row * DD);
  float4 ra[8], rb[8];
#pragma unroll
  for (int it = 0; it < 8; ++it) ra[it] = a[it * 64 + lane];
#pragma unroll
  for (int it = 0; it < 8; ++it) rb[it] = b[it * 64 + lane];
  float acc = 0.f;
#pragma unroll
  for (int it = 0; it < 8; ++it) {
    float4 s4 = *(const float4*)&sv[4 * (it * 64 + lane)];
    acc = fmaf(ra[it].x, s4.x, acc); acc = fmaf(ra[it].y, s4.y, acc);
    acc = fmaf(ra[it].z, s4.z, acc); acc = fmaf(ra[it].w, s4.w, acc);
  }
#pragma unroll
  for (int it = 0; it < 8; ++it) {
    float4 h4 = *(const float4*)&hm[4 * (it * 64 + lane)];
    acc = fmaf(rb[it].x, h4.x, acc); acc = fmaf(rb[it].y, h4.y, acc);
    acc = fmaf(rb[it].z, h4.z, acc); acc = fmaf(rb[it].w, h4.w, acc);
  }
  acc = wred(acc);
  if (lane == 0) gates_m[row] = acc + bih_m[row] + bhh_m[row];
}

// Kernel D: LSTM elementwise (manager + worker), g_hat, and all scalar
// reductions. scal: 0=norm2 1=mval 2=wval 3=num9h 4..13=dd2 14..22=num 23..31=gg2
__global__ void k_cell(const float* __restrict__ gates_m, const float* __restrict__ gates_w,
                       const int* __restrict__ tick, const float* __restrict__ hn_m,
                       const float* __restrict__ cn_m, const float* __restrict__ cn_w,
                       const float* __restrict__ Wmv, const float* __restrict__ Wc,
                       const float* __restrict__ goals, const float* __restrict__ states,
                       const float* __restrict__ s_in,
                       float* __restrict__ g_hat, float* __restrict__ goalsA,
                       float* __restrict__ u_flat, float* __restrict__ scal) {
  const int t = blockIdx.x * blockDim.x + threadIdx.x;
  const int tk = *tick;
  float r_norm2 = 0.f, r_mval = 0.f, r_wval = 0.f, r_num9h = 0.f;
  float r_dd2[10], r_num[9], r_gg2[9];
#pragma unroll
  for (int r = 0; r < 10; ++r) r_dd2[r] = 0.f;
#pragma unroll
  for (int r = 0; r < 9; ++r) { r_num[r] = 0.f; r_gg2[r] = 0.f; }

  if (t < DD) {
    const int d = t;
    float gi = gates_m[d], gf = gates_m[DD + d], gg = gates_m[2 * DD + d], go = gates_m[3 * DD + d];
    float c = cn_m[tk * DD + d];
    float c2 = sigf(gf) * c + sigf(gi) * tanhf(gg);
    float hnew = sigf(go) * tanhf(c2);
    float sum = hnew;
#pragma unroll
    for (int r = 0; r < RR; ++r) sum += (r == tk) ? 0.f : hn_m[r * DD + d];
    float gh = sum * (1.f / RR);
    g_hat[d] = gh;
    r_norm2 = gh * gh;
    r_mval = Wmv[d] * gh;
    float ga = 0.f;
    float sd = s_in[d];
#pragma unroll
    for (int r = 0; r < RR; ++r) {
      float diff = sd - states[(r + 1) * DD + d];
      r_dd2[r] = diff * diff;
      if (r < 9) {
        float gl = goals[(r + 1) * DD + d];
        ga += gl;
        r_num[r] = diff * gl;
        r_gg2[r] = gl * gl;
      } else {
        r_num9h = diff * gh;  // dot(diff9, g_hat); scaled by rnorm at finalize
      }
    }
    goalsA[d] = ga;
  } else if (t < DD + HH) {
    const int j = t - DD;
    float gi = gates_w[j], gf = gates_w[HH + j], gg = gates_w[2 * HH + j], go = gates_w[3 * HH + j];
    float c = cn_w[j];
    float c2 = sigf(gf) * c + sigf(gi) * tanhf(gg);
    float u = sigf(go) * tanhf(c2);
    u_flat[j] = u;
    r_wval = Wc[j] * u;
  }

  r_norm2 = wred(r_norm2); r_mval = wred(r_mval);
  r_wval = wred(r_wval);   r_num9h = wred(r_num9h);
#pragma unroll
  for (int r = 0; r < 10; ++r) r_dd2[r] = wred(r_dd2[r]);
#pragma unroll
  for (int r = 0; r < 9; ++r) { r_num[r] = wred(r_num[r]); r_gg2[r] = wred(r_gg2[r]); }
  if ((threadIdx.x & 63) == 0) {
    atomicAdd(&scal[0], r_norm2);
    atomicAdd(&scal[1], r_mval);
    atomicAdd(&scal[2], r_wval);
    atomicAdd(&scal[3], r_num9h);
#pragma unroll
    for (int r = 0; r < 10; ++r) atomicAdd(&scal[4 + r], r_dd2[r]);
#pragma unroll
    for (int r = 0; r < 9; ++r) {
      atomicAdd(&scal[14 + r], r_num[r]);
      atomicAdd(&scal[23 + r], r_gg2[r]);
    }
  }
}

// Kernel E: w = Wphi @ (sum(goals[1:]) + g_hat * rnorm), one wave per row.
__global__ void k_w(const float* __restrict__ Wphi, const float* __restrict__ g_hat,
                    const float* __restrict__ goalsA, const float* __restrict__ scal,
                    float* __restrict__ wv) {
  __shared__ float vsum[DD];
  const float rn = 1.f / fmaxf(sqrtf(scal[0]), 1e-12f);
  for (int i = threadIdx.x; i < DD; i += blockDim.x)
    vsum[i] = fmaf(g_hat[i], rn, goalsA[i]);
  __syncthreads();
  const int lane = threadIdx.x & 63;
  const int gw = blockIdx.x * (blockDim.x >> 6) + (threadIdx.x >> 6);
  if (gw < KK) {
    const float4* a = (const float4*)(Wphi + (size_t)gw * DD);
    float4 rw[8];
#pragma unroll
    for (int it = 0; it < 8; ++it) rw[it] = a[it * 64 + lane];
    float acc = 0.f;
#pragma unroll
    for (int it = 0; it < 8; ++it) {
      float4 v4 = *(const float4*)&vsum[4 * (it * 64 + lane)];
      acc = fmaf(rw[it].x, v4.x, acc); acc = fmaf(rw[it].y, v4.y, acc);
      acc = fmaf(rw[it].z, v4.z, acc); acc = fmaf(rw[it].w, v4.w, acc);
    }
    acc = wred(acc);
    if (lane == 0) wv[gw] = acc;
  }
}

// Kernel F: logits + scalar outputs.
__global__ void k_final(const float* __restrict__ u_flat, const float* __restrict__ wv,
                        const float* __restrict__ scal, const float* __restrict__ bmv,
                        const float* __restrict__ bc, float* __restrict__ out) {
  __shared__ float wl[KK];
  if (threadIdx.x < KK) wl[threadIdx.x] = wv[threadIdx.x];
  __syncthreads();
  const int lane = threadIdx.x & 63;
  const int wid = threadIdx.x >> 6;
  const int nw = blockDim.x >> 6;
  for (int a = wid; a < NAA; a += nw) {
    float acc = u_flat[a * KK + lane] * wl[lane];
    acc = wred(acc);
    if (lane == 0) out[a] = acc;
  }
  if (threadIdx.x == 0) {
    float nrm = sqrtf(scal[0]);
    float rn = 1.f / fmaxf(nrm, 1e-12f);
    float gnorm = nrm * rn;  // ||g|| exactly as reference
    float csum = 0.f;
    for (int r = 0; r < 9; ++r) {
      float den = fmaxf(sqrtf(scal[4 + r]), 1e-8f) * fmaxf(sqrtf(scal[23 + r]), 1e-8f);
      csum += scal[14 + r] / den;
    }
    float den9 = fmaxf(sqrtf(scal[13]), 1e-8f) * fmaxf(gnorm, 1e-8f);
    csum += (scal[3] * rn) / den9;
    out[NAA] = (float)DD * csum / 10.f;   // w_intrinsic_reward
    out[NAA + 1] = scal[2] + bc[0];       // w_value
    out[NAA + 2] = scal[1] + bmv[0];      // m_value
  }
}

extern "C" void kernel_launch(void* const* d_in, const int* in_sizes, int n_in,
                              void* d_out, int out_size, void* d_ws, size_t ws_size,
                              hipStream_t stream) {
  const float* x      = (const float*)d_in[0];
  const float* Wp     = (const float*)d_in[1];
  const float* bp     = (const float*)d_in[2];
  const float* Wms    = (const float*)d_in[3];
  const float* bms    = (const float*)d_in[4];
  const float* Wih_m  = (const float*)d_in[5];
  const float* Whh_m  = (const float*)d_in[6];
  const float* bih_m  = (const float*)d_in[7];
  const float* bhh_m  = (const float*)d_in[8];
  const float* hn_m   = (const float*)d_in[9];
  const float* cn_m   = (const float*)d_in[10];
  const float* Wmv    = (const float*)d_in[11];
  const float* bmv    = (const float*)d_in[12];
  const float* Wih_w  = (const float*)d_in[13];
  const float* Whh_w  = (const float*)d_in[14];
  const float* bih_w  = (const float*)d_in[15];
  const float* bhh_w  = (const float*)d_in[16];
  const float* hn_w   = (const float*)d_in[17];
  const float* cn_w   = (const float*)d_in[18];
  const float* Wphi   = (const float*)d_in[19];
  const float* Wc     = (const float*)d_in[20];
  const float* bc     = (const float*)d_in[21];
  const float* states = (const float*)d_in[22];
  const float* goals  = (const float*)d_in[23];
  const int*   tick   = (const int*)d_in[24];

  float* ws      = (float*)d_ws;
  float* gates_m = ws;             // 8192
  float* gates_w = ws + 8192;      // 4608
  float* s_buf   = ws + 12800;     // 2048
  float* g_hat   = ws + 14848;     // 2048
  float* goalsA  = ws + 16896;     // 2048
  float* u_flat  = ws + 18944;     // 1152
  float* wvec    = ws + 20096;     // 64
  float* scal    = ws + 20160;     // 32
  float* out     = (float*)d_out;

  // Worker gates first (no dependency on s), then s, then manager gates.
  hipLaunchKernelGGL(k_wg, dim3(1152), dim3(256), 0, stream,
                     x, Wp, bp, Wih_w, Whh_w, bih_w, bhh_w, hn_w, gates_w);
  hipLaunchKernelGGL(k_s, dim3(512), dim3(256), 0, stream,
                     x, Wp, bp, Wms, bms, s_buf, scal);
  hipLaunchKernelGGL(k_mg, dim3(2048), dim3(256), 0, stream,
                     s_buf, tick, Wih_m, Whh_m, bih_m, bhh_m, hn_m, gates_m);
  hipLaunchKernelGGL(k_cell, dim3(13), dim3(256), 0, stream,
                     gates_m, gates_w, tick, hn_m, cn_m, cn_w, Wmv, Wc,
                     goals, states, s_buf, g_hat, goalsA, u_flat, scal);
  hipLaunchKernelGGL(k_w, dim3(16), dim3(256), 0, stream,
                     Wphi, g_hat, goalsA, scal, wvec);
  hipLaunchKernelGGL(k_final, dim3(1), dim3(512), 0, stream,
                     u_flat, wvec, scal, bmv, bc, out);
}

// Round 5
// 275.121 us; speedup vs baseline: 1.0583x; 1.0485x over previous
//
#include <hip/hip_runtime.h>
#include <math.h>

#define DD 2048
#define HH 1152
#define NAA 18
#define KK 64
#define RR 10

typedef float f32x4 __attribute__((ext_vector_type(4)));

__device__ __forceinline__ f32x4 ntl4(const float* p) {
  return __builtin_nontemporal_load((const f32x4*)p);
}
__device__ __forceinline__ f32x4 lds4(const float* p) {
  return *(const f32x4*)p;
}

__device__ __forceinline__ float wred(float v) {
#pragma unroll
  for (int off = 32; off > 0; off >>= 1) v += __shfl_down(v, off);
  return v;
}

__device__ __forceinline__ float sigf(float x) { return 1.f / (1.f + expf(-x)); }

// K1: s = relu(Wms @ z + bms); z recomputed in LDS; zero the scal accumulators.
__global__ __launch_bounds__(256) void k1_s(
    const float* __restrict__ x, const float* __restrict__ Wp,
    const float* __restrict__ bp, const float* __restrict__ Wms,
    const float* __restrict__ bms, float* __restrict__ s_out,
    float* __restrict__ scal) {
  __shared__ float z[DD];
  const float x0 = x[0], x1 = x[1];
  for (int i = threadIdx.x; i < DD; i += blockDim.x) {
    float v = fmaf(Wp[2 * i], x0, fmaf(Wp[2 * i + 1], x1, bp[i]));
    z[i] = fmaxf(v, 0.f);
  }
  if (blockIdx.x == 0 && threadIdx.x < 32) scal[threadIdx.x] = 0.f;
  __syncthreads();
  const int lane = threadIdx.x & 63;
  const int row = blockIdx.x * 4 + (threadIdx.x >> 6);
  if (row >= DD) return;
  const float* a = Wms + (size_t)row * DD;
  float acc = 0.f;
#pragma unroll
  for (int it = 0; it < 8; ++it) {
    f32x4 w4 = ntl4(a + 4 * (it * 64 + lane));
    f32x4 z4 = lds4(&z[4 * (it * 64 + lane)]);
    acc = fmaf(w4[0], z4[0], acc); acc = fmaf(w4[1], z4[1], acc);
    acc = fmaf(w4[2], z4[2], acc); acc = fmaf(w4[3], z4[3], acc);
  }
  acc = wred(acc);
  if (lane == 0) s_out[row] = fmaxf(acc + bms[row], 0.f);
}

// K2: ALL LSTM gate matvecs (manager 8192 rows + worker 4608 rows, 193 MB).
// One row per wave; weights via nontemporal loads (no L2/L3 allocation).
__global__ __launch_bounds__(256) void k2_gates(
    const float* __restrict__ x, const float* __restrict__ Wp,
    const float* __restrict__ bp, const float* __restrict__ s_in,
    const int* __restrict__ tick,
    const float* __restrict__ Wih_m, const float* __restrict__ Whh_m,
    const float* __restrict__ bih_m, const float* __restrict__ bhh_m,
    const float* __restrict__ hn_m,
    const float* __restrict__ Wih_w, const float* __restrict__ Whh_w,
    const float* __restrict__ bih_w, const float* __restrict__ bhh_w,
    const float* __restrict__ hn_w,
    float* __restrict__ gates_m, float* __restrict__ gates_w) {
  __shared__ float sv[DD];
  __shared__ float zv[DD];
  __shared__ float hm[DD];
  __shared__ float hw[HH];
  const int tk = *tick;
  const float x0 = x[0], x1 = x[1];
  for (int i = threadIdx.x; i < DD; i += blockDim.x) {
    sv[i] = s_in[i];
    float v = fmaf(Wp[2 * i], x0, fmaf(Wp[2 * i + 1], x1, bp[i]));
    zv[i] = fmaxf(v, 0.f);
    hm[i] = hn_m[tk * DD + i];
  }
  for (int i = threadIdx.x; i < HH; i += blockDim.x) hw[i] = hn_w[i];
  __syncthreads();
  const int lane = threadIdx.x & 63;
  const int row = blockIdx.x * 4 + (threadIdx.x >> 6);
  if (row < 4 * DD) {
    const float* a = Wih_m + (size_t)row * DD;
    const float* b = Whh_m + (size_t)row * DD;
    float acc = 0.f;
#pragma unroll
    for (int it = 0; it < 8; ++it) {
      f32x4 a4 = ntl4(a + 4 * (it * 64 + lane));
      f32x4 s4 = lds4(&sv[4 * (it * 64 + lane)]);
      acc = fmaf(a4[0], s4[0], acc); acc = fmaf(a4[1], s4[1], acc);
      acc = fmaf(a4[2], s4[2], acc); acc = fmaf(a4[3], s4[3], acc);
    }
#pragma unroll
    for (int it = 0; it < 8; ++it) {
      f32x4 b4 = ntl4(b + 4 * (it * 64 + lane));
      f32x4 h4 = lds4(&hm[4 * (it * 64 + lane)]);
      acc = fmaf(b4[0], h4[0], acc); acc = fmaf(b4[1], h4[1], acc);
      acc = fmaf(b4[2], h4[2], acc); acc = fmaf(b4[3], h4[3], acc);
    }
    acc = wred(acc);
    if (lane == 0) gates_m[row] = acc + bih_m[row] + bhh_m[row];
  } else {
    const int j = row - 4 * DD;
    if (j >= 4 * HH) return;
    const float* a = Wih_w + (size_t)j * DD;
    const float* b = Whh_w + (size_t)j * HH;
    float acc = 0.f;
#pragma unroll
    for (int it = 0; it < 8; ++it) {
      f32x4 a4 = ntl4(a + 4 * (it * 64 + lane));
      f32x4 z4 = lds4(&zv[4 * (it * 64 + lane)]);
      acc = fmaf(a4[0], z4[0], acc); acc = fmaf(a4[1], z4[1], acc);
      acc = fmaf(a4[2], z4[2], acc); acc = fmaf(a4[3], z4[3], acc);
    }
#pragma unroll
    for (int it = 0; it < 4; ++it) {
      f32x4 b4 = ntl4(b + 4 * (it * 64 + lane));
      f32x4 h4 = lds4(&hw[4 * (it * 64 + lane)]);
      acc = fmaf(b4[0], h4[0], acc); acc = fmaf(b4[1], h4[1], acc);
      acc = fmaf(b4[2], h4[2], acc); acc = fmaf(b4[3], h4[3], acc);
    }
    if (lane < 32) {
      f32x4 b4 = ntl4(b + 4 * (256 + lane));
      f32x4 h4 = lds4(&hw[4 * (256 + lane)]);
      acc = fmaf(b4[0], h4[0], acc); acc = fmaf(b4[1], h4[1], acc);
      acc = fmaf(b4[2], h4[2], acc); acc = fmaf(b4[3], h4[3], acc);
    }
    acc = wred(acc);
    if (lane == 0) gates_w[j] = acc + bih_w[j] + bhh_w[j];
  }
}

// K3: LSTM elementwise (manager + worker), g_hat, and all scalar reductions.
// scal: 0=norm2 1=mval 2=wval 3=num9h 4..13=dd2 14..22=num 23..31=gg2
__global__ void k3_cell(const float* __restrict__ gates_m, const float* __restrict__ gates_w,
                        const int* __restrict__ tick, const float* __restrict__ hn_m,
                        const float* __restrict__ cn_m, const float* __restrict__ cn_w,
                        const float* __restrict__ Wmv, const float* __restrict__ Wc,
                        const float* __restrict__ goals, const float* __restrict__ states,
                        const float* __restrict__ s_in,
                        float* __restrict__ g_hat, float* __restrict__ goalsA,
                        float* __restrict__ u_flat, float* __restrict__ scal) {
  const int t = blockIdx.x * blockDim.x + threadIdx.x;
  const int tk = *tick;
  float r_norm2 = 0.f, r_mval = 0.f, r_wval = 0.f, r_num9h = 0.f;
  float r_dd2[10], r_num[9], r_gg2[9];
#pragma unroll
  for (int r = 0; r < 10; ++r) r_dd2[r] = 0.f;
#pragma unroll
  for (int r = 0; r < 9; ++r) { r_num[r] = 0.f; r_gg2[r] = 0.f; }

  if (t < DD) {
    const int d = t;
    float gi = gates_m[d], gf = gates_m[DD + d], gg = gates_m[2 * DD + d], go = gates_m[3 * DD + d];
    float c = cn_m[tk * DD + d];
    float c2 = sigf(gf) * c + sigf(gi) * tanhf(gg);
    float hnew = sigf(go) * tanhf(c2);
    float sum = hnew;
#pragma unroll
    for (int r = 0; r < RR; ++r) sum += (r == tk) ? 0.f : hn_m[r * DD + d];
    float gh = sum * (1.f / RR);
    g_hat[d] = gh;
    r_norm2 = gh * gh;
    r_mval = Wmv[d] * gh;
    float ga = 0.f;
    float sd = s_in[d];
#pragma unroll
    for (int r = 0; r < RR; ++r) {
      float diff = sd - states[(r + 1) * DD + d];
      r_dd2[r] = diff * diff;
      if (r < 9) {
        float gl = goals[(r + 1) * DD + d];
        ga += gl;
        r_num[r] = diff * gl;
        r_gg2[r] = gl * gl;
      } else {
        r_num9h = diff * gh;  // dot(diff9, g_hat); scaled by rnorm at finalize
      }
    }
    goalsA[d] = ga;
  } else if (t < DD + HH) {
    const int j = t - DD;
    float gi = gates_w[j], gf = gates_w[HH + j], gg = gates_w[2 * HH + j], go = gates_w[3 * HH + j];
    float c = cn_w[j];
    float c2 = sigf(gf) * c + sigf(gi) * tanhf(gg);
    float u = sigf(go) * tanhf(c2);
    u_flat[j] = u;
    r_wval = Wc[j] * u;
  }

  r_norm2 = wred(r_norm2); r_mval = wred(r_mval);
  r_wval = wred(r_wval);   r_num9h = wred(r_num9h);
#pragma unroll
  for (int r = 0; r < 10; ++r) r_dd2[r] = wred(r_dd2[r]);
#pragma unroll
  for (int r = 0; r < 9; ++r) { r_num[r] = wred(r_num[r]); r_gg2[r] = wred(r_gg2[r]); }
  if ((threadIdx.x & 63) == 0) {
    atomicAdd(&scal[0], r_norm2);
    atomicAdd(&scal[1], r_mval);
    atomicAdd(&scal[2], r_wval);
    atomicAdd(&scal[3], r_num9h);
#pragma unroll
    for (int r = 0; r < 10; ++r) atomicAdd(&scal[4 + r], r_dd2[r]);
#pragma unroll
    for (int r = 0; r < 9; ++r) {
      atomicAdd(&scal[14 + r], r_num[r]);
      atomicAdd(&scal[23 + r], r_gg2[r]);
    }
  }
}

// K4: w = Wphi@(goalsA + g_hat*rn), logits, and scalar outputs. One block.
__global__ __launch_bounds__(1024) void k4_wf(
    const float* __restrict__ Wphi, const float* __restrict__ g_hat,
    const float* __restrict__ goalsA, const float* __restrict__ u_flat,
    const float* __restrict__ scal, const float* __restrict__ bmv,
    const float* __restrict__ bc, float* __restrict__ out) {
  __shared__ float vsum[DD];
  __shared__ float wl[KK];
  const float rn = 1.f / fmaxf(sqrtf(scal[0]), 1e-12f);
  for (int i = threadIdx.x; i < DD; i += blockDim.x)
    vsum[i] = fmaf(g_hat[i], rn, goalsA[i]);
  __syncthreads();
  const int lane = threadIdx.x & 63;
  const int wid = threadIdx.x >> 6;  // 0..15
#pragma unroll
  for (int i = 0; i < 4; ++i) {
    const int row = wid * 4 + i;  // 0..63
    const float* a = Wphi + (size_t)row * DD;
    float acc = 0.f;
#pragma unroll
    for (int it = 0; it < 8; ++it) {
      f32x4 a4 = lds4(a + 4 * (it * 64 + lane));  // normal load, tiny matrix
      f32x4 v4 = lds4(&vsum[4 * (it * 64 + lane)]);
      acc = fmaf(a4[0], v4[0], acc); acc = fmaf(a4[1], v4[1], acc);
      acc = fmaf(a4[2], v4[2], acc); acc = fmaf(a4[3], v4[3], acc);
    }
    acc = wred(acc);
    if (lane == 0) wl[row] = acc;
  }
  __syncthreads();
  for (int a = wid; a < NAA; a += 16) {
    float acc = u_flat[a * KK + lane] * wl[lane];
    acc = wred(acc);
    if (lane == 0) out[a] = acc;
  }
  if (threadIdx.x == 0) {
    float nrm = sqrtf(scal[0]);
    float rnn = 1.f / fmaxf(nrm, 1e-12f);
    float gnorm = nrm * rnn;
    float csum = 0.f;
    for (int r = 0; r < 9; ++r) {
      float den = fmaxf(sqrtf(scal[4 + r]), 1e-8f) * fmaxf(sqrtf(scal[23 + r]), 1e-8f);
      csum += scal[14 + r] / den;
    }
    float den9 = fmaxf(sqrtf(scal[13]), 1e-8f) * fmaxf(gnorm, 1e-8f);
    csum += (scal[3] * rnn) / den9;
    out[NAA] = (float)DD * csum / 10.f;   // w_intrinsic_reward
    out[NAA + 1] = scal[2] + bc[0];       // w_value
    out[NAA + 2] = scal[1] + bmv[0];      // m_value
  }
}

extern "C" void kernel_launch(void* const* d_in, const int* in_sizes, int n_in,
                              void* d_out, int out_size, void* d_ws, size_t ws_size,
                              hipStream_t stream) {
  const float* x      = (const float*)d_in[0];
  const float* Wp     = (const float*)d_in[1];
  const float* bp     = (const float*)d_in[2];
  const float* Wms    = (const float*)d_in[3];
  const float* bms    = (const float*)d_in[4];
  const float* Wih_m  = (const float*)d_in[5];
  const float* Whh_m  = (const float*)d_in[6];
  const float* bih_m  = (const float*)d_in[7];
  const float* bhh_m  = (const float*)d_in[8];
  const float* hn_m   = (const float*)d_in[9];
  const float* cn_m   = (const float*)d_in[10];
  const float* Wmv    = (const float*)d_in[11];
  const float* bmv    = (const float*)d_in[12];
  const float* Wih_w  = (const float*)d_in[13];
  const float* Whh_w  = (const float*)d_in[14];
  const float* bih_w  = (const float*)d_in[15];
  const float* bhh_w  = (const float*)d_in[16];
  const float* hn_w   = (const float*)d_in[17];
  const float* cn_w   = (const float*)d_in[18];
  const float* Wphi   = (const float*)d_in[19];
  const float* Wc     = (const float*)d_in[20];
  const float* bc     = (const float*)d_in[21];
  const float* states = (const float*)d_in[22];
  const float* goals  = (const float*)d_in[23];
  const int*   tick   = (const int*)d_in[24];

  float* ws      = (float*)d_ws;
  float* gates_m = ws;             // 8192
  float* gates_w = ws + 8192;      // 4608
  float* s_buf   = ws + 12800;     // 2048
  float* g_hat   = ws + 14848;     // 2048
  float* goalsA  = ws + 16896;     // 2048
  float* u_flat  = ws + 18944;     // 1152
  float* scal    = ws + 20160;     // 32
  float* out     = (float*)d_out;

  hipLaunchKernelGGL(k1_s, dim3(512), dim3(256), 0, stream,
                     x, Wp, bp, Wms, bms, s_buf, scal);
  hipLaunchKernelGGL(k2_gates, dim3(3200), dim3(256), 0, stream,
                     x, Wp, bp, s_buf, tick,
                     Wih_m, Whh_m, bih_m, bhh_m, hn_m,
                     Wih_w, Whh_w, bih_w, bhh_w, hn_w,
                     gates_m, gates_w);
  hipLaunchKernelGGL(k3_cell, dim3(13), dim3(256), 0, stream,
                     gates_m, gates_w, tick, hn_m, cn_m, cn_w, Wmv, Wc,
                     goals, states, s_buf, g_hat, goalsA, u_flat, scal);
  hipLaunchKernelGGL(k4_wf, dim3(1), dim3(1024), 0, stream,
                     Wphi, g_hat, goalsA, u_flat, scal, bmv, bc, out);
}

// Round 6
// 274.505 us; speedup vs baseline: 1.0607x; 1.0022x over previous
//
#include <hip/hip_runtime.h>
#include <math.h>

#define DD 2048
#define HH 1152
#define NAA 18
#define KK 64
#define RR 10

typedef float f32x4 __attribute__((ext_vector_type(4)));

__device__ __forceinline__ f32x4 ntl4(const float* p) {
  return __builtin_nontemporal_load((const f32x4*)p);
}
__device__ __forceinline__ f32x4 lds4(const float* p) {
  return *(const f32x4*)p;
}

__device__ __forceinline__ float wred(float v) {
#pragma unroll
  for (int off = 32; off > 0; off >>= 1) v += __shfl_down(v, off);
  return v;
}

__device__ __forceinline__ float sigf(float x) { return 1.f / (1.f + expf(-x)); }

// K1: s = relu(Wms @ z + bms); z recomputed in LDS; zero the scal accumulators.
// 8 NT loads batched ahead of compute via sched_barrier.
__global__ __launch_bounds__(256, 2) void k1_s(
    const float* __restrict__ x, const float* __restrict__ Wp,
    const float* __restrict__ bp, const float* __restrict__ Wms,
    const float* __restrict__ bms, float* __restrict__ s_out,
    float* __restrict__ scal) {
  __shared__ float z[DD];
  const float x0 = x[0], x1 = x[1];
  for (int i = threadIdx.x; i < DD; i += blockDim.x) {
    float v = fmaf(Wp[2 * i], x0, fmaf(Wp[2 * i + 1], x1, bp[i]));
    z[i] = fmaxf(v, 0.f);
  }
  if (blockIdx.x == 0 && threadIdx.x < 32) scal[threadIdx.x] = 0.f;
  __syncthreads();
  const int lane = threadIdx.x & 63;
  const int row = blockIdx.x * 4 + (threadIdx.x >> 6);
  if (row >= DD) return;
  const float* a = Wms + (size_t)row * DD;
  f32x4 ra[8];
#pragma unroll
  for (int it = 0; it < 8; ++it) ra[it] = ntl4(a + 4 * (it * 64 + lane));
  __builtin_amdgcn_sched_barrier(0);  // keep all 8 loads issued before compute
  float acc = 0.f;
#pragma unroll
  for (int it = 0; it < 8; ++it) {
    f32x4 z4 = lds4(&z[4 * (it * 64 + lane)]);
    acc = fmaf(ra[it][0], z4[0], acc); acc = fmaf(ra[it][1], z4[1], acc);
    acc = fmaf(ra[it][2], z4[2], acc); acc = fmaf(ra[it][3], z4[3], acc);
  }
  acc = wred(acc);
  if (lane == 0) s_out[row] = fmaxf(acc + bms[row], 0.f);
}

// K2: ALL LSTM gate matvecs (manager 8192 rows + worker 4608 rows, 193 MB).
// One row per wave; 16 NT loads batched in-registers before any FMA.
__global__ __launch_bounds__(256, 2) void k2_gates(
    const float* __restrict__ x, const float* __restrict__ Wp,
    const float* __restrict__ bp, const float* __restrict__ s_in,
    const int* __restrict__ tick,
    const float* __restrict__ Wih_m, const float* __restrict__ Whh_m,
    const float* __restrict__ bih_m, const float* __restrict__ bhh_m,
    const float* __restrict__ hn_m,
    const float* __restrict__ Wih_w, const float* __restrict__ Whh_w,
    const float* __restrict__ bih_w, const float* __restrict__ bhh_w,
    const float* __restrict__ hn_w,
    float* __restrict__ gates_m, float* __restrict__ gates_w) {
  __shared__ float sv[DD];
  __shared__ float zv[DD];
  __shared__ float hm[DD];
  __shared__ float hw[HH];
  const int tk = *tick;
  const float x0 = x[0], x1 = x[1];
  for (int i = threadIdx.x; i < DD; i += blockDim.x) {
    sv[i] = s_in[i];
    float v = fmaf(Wp[2 * i], x0, fmaf(Wp[2 * i + 1], x1, bp[i]));
    zv[i] = fmaxf(v, 0.f);
    hm[i] = hn_m[tk * DD + i];
  }
  for (int i = threadIdx.x; i < HH; i += blockDim.x) hw[i] = hn_w[i];
  __syncthreads();
  const int lane = threadIdx.x & 63;
  const int row = blockIdx.x * 4 + (threadIdx.x >> 6);
  if (row < 4 * DD) {
    const float* a = Wih_m + (size_t)row * DD;
    const float* b = Whh_m + (size_t)row * DD;
    f32x4 ra[8], rb[8];
#pragma unroll
    for (int it = 0; it < 8; ++it) ra[it] = ntl4(a + 4 * (it * 64 + lane));
#pragma unroll
    for (int it = 0; it < 8; ++it) rb[it] = ntl4(b + 4 * (it * 64 + lane));
    __builtin_amdgcn_sched_barrier(0);  // all 16 loads in flight before compute
    float acc = 0.f;
#pragma unroll
    for (int it = 0; it < 8; ++it) {
      f32x4 s4 = lds4(&sv[4 * (it * 64 + lane)]);
      acc = fmaf(ra[it][0], s4[0], acc); acc = fmaf(ra[it][1], s4[1], acc);
      acc = fmaf(ra[it][2], s4[2], acc); acc = fmaf(ra[it][3], s4[3], acc);
    }
#pragma unroll
    for (int it = 0; it < 8; ++it) {
      f32x4 h4 = lds4(&hm[4 * (it * 64 + lane)]);
      acc = fmaf(rb[it][0], h4[0], acc); acc = fmaf(rb[it][1], h4[1], acc);
      acc = fmaf(rb[it][2], h4[2], acc); acc = fmaf(rb[it][3], h4[3], acc);
    }
    acc = wred(acc);
    if (lane == 0) gates_m[row] = acc + bih_m[row] + bhh_m[row];
  } else {
    const int j = row - 4 * DD;
    if (j >= 4 * HH) return;
    const float* a = Wih_w + (size_t)j * DD;
    const float* b = Whh_w + (size_t)j * HH;
    f32x4 ra[8], rb[5];
#pragma unroll
    for (int it = 0; it < 8; ++it) ra[it] = ntl4(a + 4 * (it * 64 + lane));
#pragma unroll
    for (int it = 0; it < 4; ++it) rb[it] = ntl4(b + 4 * (it * 64 + lane));
    rb[4] = (lane < 32) ? ntl4(b + 4 * (256 + lane)) : f32x4{0.f, 0.f, 0.f, 0.f};
    __builtin_amdgcn_sched_barrier(0);
    float acc = 0.f;
#pragma unroll
    for (int it = 0; it < 8; ++it) {
      f32x4 z4 = lds4(&zv[4 * (it * 64 + lane)]);
      acc = fmaf(ra[it][0], z4[0], acc); acc = fmaf(ra[it][1], z4[1], acc);
      acc = fmaf(ra[it][2], z4[2], acc); acc = fmaf(ra[it][3], z4[3], acc);
    }
#pragma unroll
    for (int it = 0; it < 4; ++it) {
      f32x4 h4 = lds4(&hw[4 * (it * 64 + lane)]);
      acc = fmaf(rb[it][0], h4[0], acc); acc = fmaf(rb[it][1], h4[1], acc);
      acc = fmaf(rb[it][2], h4[2], acc); acc = fmaf(rb[it][3], h4[3], acc);
    }
    {
      f32x4 h4 = lds4(&hw[4 * (256 + (lane & 31))]);
      acc = fmaf(rb[4][0], h4[0], acc); acc = fmaf(rb[4][1], h4[1], acc);
      acc = fmaf(rb[4][2], h4[2], acc); acc = fmaf(rb[4][3], h4[3], acc);
    }
    acc = wred(acc);
    if (lane == 0) gates_w[j] = acc + bih_w[j] + bhh_w[j];
  }
}

// K3: LSTM elementwise (manager + worker), g_hat, and all scalar reductions.
// scal: 0=norm2 1=mval 2=wval 3=num9h 4..13=dd2 14..22=num 23..31=gg2
__global__ void k3_cell(const float* __restrict__ gates_m, const float* __restrict__ gates_w,
                        const int* __restrict__ tick, const float* __restrict__ hn_m,
                        const float* __restrict__ cn_m, const float* __restrict__ cn_w,
                        const float* __restrict__ Wmv, const float* __restrict__ Wc,
                        const float* __restrict__ goals, const float* __restrict__ states,
                        const float* __restrict__ s_in,
                        float* __restrict__ g_hat, float* __restrict__ goalsA,
                        float* __restrict__ u_flat, float* __restrict__ scal) {
  const int t = blockIdx.x * blockDim.x + threadIdx.x;
  const int tk = *tick;
  float r_norm2 = 0.f, r_mval = 0.f, r_wval = 0.f, r_num9h = 0.f;
  float r_dd2[10], r_num[9], r_gg2[9];
#pragma unroll
  for (int r = 0; r < 10; ++r) r_dd2[r] = 0.f;
#pragma unroll
  for (int r = 0; r < 9; ++r) { r_num[r] = 0.f; r_gg2[r] = 0.f; }

  if (t < DD) {
    const int d = t;
    float gi = gates_m[d], gf = gates_m[DD + d], gg = gates_m[2 * DD + d], go = gates_m[3 * DD + d];
    float c = cn_m[tk * DD + d];
    float c2 = sigf(gf) * c + sigf(gi) * tanhf(gg);
    float hnew = sigf(go) * tanhf(c2);
    float sum = hnew;
#pragma unroll
    for (int r = 0; r < RR; ++r) sum += (r == tk) ? 0.f : hn_m[r * DD + d];
    float gh = sum * (1.f / RR);
    g_hat[d] = gh;
    r_norm2 = gh * gh;
    r_mval = Wmv[d] * gh;
    float ga = 0.f;
    float sd = s_in[d];
#pragma unroll
    for (int r = 0; r < RR; ++r) {
      float diff = sd - states[(r + 1) * DD + d];
      r_dd2[r] = diff * diff;
      if (r < 9) {
        float gl = goals[(r + 1) * DD + d];
        ga += gl;
        r_num[r] = diff * gl;
        r_gg2[r] = gl * gl;
      } else {
        r_num9h = diff * gh;  // dot(diff9, g_hat); scaled by rnorm at finalize
      }
    }
    goalsA[d] = ga;
  } else if (t < DD + HH) {
    const int j = t - DD;
    float gi = gates_w[j], gf = gates_w[HH + j], gg = gates_w[2 * HH + j], go = gates_w[3 * HH + j];
    float c = cn_w[j];
    float c2 = sigf(gf) * c + sigf(gi) * tanhf(gg);
    float u = sigf(go) * tanhf(c2);
    u_flat[j] = u;
    r_wval = Wc[j] * u;
  }

  r_norm2 = wred(r_norm2); r_mval = wred(r_mval);
  r_wval = wred(r_wval);   r_num9h = wred(r_num9h);
#pragma unroll
  for (int r = 0; r < 10; ++r) r_dd2[r] = wred(r_dd2[r]);
#pragma unroll
  for (int r = 0; r < 9; ++r) { r_num[r] = wred(r_num[r]); r_gg2[r] = wred(r_gg2[r]); }
  if ((threadIdx.x & 63) == 0) {
    atomicAdd(&scal[0], r_norm2);
    atomicAdd(&scal[1], r_mval);
    atomicAdd(&scal[2], r_wval);
    atomicAdd(&scal[3], r_num9h);
#pragma unroll
    for (int r = 0; r < 10; ++r) atomicAdd(&scal[4 + r], r_dd2[r]);
#pragma unroll
    for (int r = 0; r < 9; ++r) {
      atomicAdd(&scal[14 + r], r_num[r]);
      atomicAdd(&scal[23 + r], r_gg2[r]);
    }
  }
}

// K4: w = Wphi@(goalsA + g_hat*rn), logits, and scalar outputs. One block.
__global__ __launch_bounds__(1024) void k4_wf(
    const float* __restrict__ Wphi, const float* __restrict__ g_hat,
    const float* __restrict__ goalsA, const float* __restrict__ u_flat,
    const float* __restrict__ scal, const float* __restrict__ bmv,
    const float* __restrict__ bc, float* __restrict__ out) {
  __shared__ float vsum[DD];
  __shared__ float wl[KK];
  const float rn = 1.f / fmaxf(sqrtf(scal[0]), 1e-12f);
  for (int i = threadIdx.x; i < DD; i += blockDim.x)
    vsum[i] = fmaf(g_hat[i], rn, goalsA[i]);
  __syncthreads();
  const int lane = threadIdx.x & 63;
  const int wid = threadIdx.x >> 6;  // 0..15
#pragma unroll
  for (int i = 0; i < 4; ++i) {
    const int row = wid * 4 + i;  // 0..63
    const float* a = Wphi + (size_t)row * DD;
    float acc = 0.f;
#pragma unroll
    for (int it = 0; it < 8; ++it) {
      f32x4 a4 = lds4(a + 4 * (it * 64 + lane));
      f32x4 v4 = lds4(&vsum[4 * (it * 64 + lane)]);
      acc = fmaf(a4[0], v4[0], acc); acc = fmaf(a4[1], v4[1], acc);
      acc = fmaf(a4[2], v4[2], acc); acc = fmaf(a4[3], v4[3], acc);
    }
    acc = wred(acc);
    if (lane == 0) wl[row] = acc;
  }
  __syncthreads();
  for (int a = wid; a < NAA; a += 16) {
    float acc = u_flat[a * KK + lane] * wl[lane];
    acc = wred(acc);
    if (lane == 0) out[a] = acc;
  }
  if (threadIdx.x == 0) {
    float nrm = sqrtf(scal[0]);
    float rnn = 1.f / fmaxf(nrm, 1e-12f);
    float gnorm = nrm * rnn;
    float csum = 0.f;
    for (int r = 0; r < 9; ++r) {
      float den = fmaxf(sqrtf(scal[4 + r]), 1e-8f) * fmaxf(sqrtf(scal[23 + r]), 1e-8f);
      csum += scal[14 + r] / den;
    }
    float den9 = fmaxf(sqrtf(scal[13]), 1e-8f) * fmaxf(gnorm, 1e-8f);
    csum += (scal[3] * rnn) / den9;
    out[NAA] = (float)DD * csum / 10.f;   // w_intrinsic_reward
    out[NAA + 1] = scal[2] + bc[0];       // w_value
    out[NAA + 2] = scal[1] + bmv[0];      // m_value
  }
}

extern "C" void kernel_launch(void* const* d_in, const int* in_sizes, int n_in,
                              void* d_out, int out_size, void* d_ws, size_t ws_size,
                              hipStream_t stream) {
  const float* x      = (const float*)d_in[0];
  const float* Wp     = (const float*)d_in[1];
  const float* bp     = (const float*)d_in[2];
  const float* Wms    = (const float*)d_in[3];
  const float* bms    = (const float*)d_in[4];
  const float* Wih_m  = (const float*)d_in[5];
  const float* Whh_m  = (const float*)d_in[6];
  const float* bih_m  = (const float*)d_in[7];
  const float* bhh_m  = (const float*)d_in[8];
  const float* hn_m   = (const float*)d_in[9];
  const float* cn_m   = (const float*)d_in[10];
  const float* Wmv    = (const float*)d_in[11];
  const float* bmv    = (const float*)d_in[12];
  const float* Wih_w  = (const float*)d_in[13];
  const float* Whh_w  = (const float*)d_in[14];
  const float* bih_w  = (const float*)d_in[15];
  const float* bhh_w  = (const float*)d_in[16];
  const float* hn_w   = (const float*)d_in[17];
  const float* cn_w   = (const float*)d_in[18];
  const float* Wphi   = (const float*)d_in[19];
  const float* Wc     = (const float*)d_in[20];
  const float* bc     = (const float*)d_in[21];
  const float* states = (const float*)d_in[22];
  const float* goals  = (const float*)d_in[23];
  const int*   tick   = (const int*)d_in[24];

  float* ws      = (float*)d_ws;
  float* gates_m = ws;             // 8192
  float* gates_w = ws + 8192;      // 4608
  float* s_buf   = ws + 12800;     // 2048
  float* g_hat   = ws + 14848;     // 2048
  float* goalsA  = ws + 16896;     // 2048
  float* u_flat  = ws + 18944;     // 1152
  float* scal    = ws + 20160;     // 32
  float* out     = (float*)d_out;

  hipLaunchKernelGGL(k1_s, dim3(512), dim3(256), 0, stream,
                     x, Wp, bp, Wms, bms, s_buf, scal);
  hipLaunchKernelGGL(k2_gates, dim3(3200), dim3(256), 0, stream,
                     x, Wp, bp, s_buf, tick,
                     Wih_m, Whh_m, bih_m, bhh_m, hn_m,
                     Wih_w, Whh_w, bih_w, bhh_w, hn_w,
                     gates_m, gates_w);
  hipLaunchKernelGGL(k3_cell, dim3(13), dim3(256), 0, stream,
                     gates_m, gates_w, tick, hn_m, cn_m, cn_w, Wmv, Wc,
                     goals, states, s_buf, g_hat, goalsA, u_flat, scal);
  hipLaunchKernelGGL(k4_wf, dim3(1), dim3(1024), 0, stream,
                     Wphi, g_hat, goalsA, u_flat, scal, bmv, bc, out);
}